// Round 2
// baseline (9711.729 us; speedup 1.0000x reference)
//
#include <hip/hip_runtime.h>
#include <hip/hip_bf16.h>

typedef short bf16x8 __attribute__((ext_vector_type(8)));
typedef float fx4 __attribute__((ext_vector_type(4)));
typedef unsigned short u16;
typedef u16 u16x4 __attribute__((ext_vector_type(4)));

#define TT 512
#define BB 64
#define II 256
#define HH 512
#define OO 256
#define GRID_WG 128

__device__ __forceinline__ u16 f2bf(float f) {
    union { float f; unsigned u; } v; v.f = f;
    unsigned r = v.u + 0x7fffu + ((v.u >> 16) & 1u);
    return (u16)(r >> 16);
}

__device__ __forceinline__ float fsig(float x) {
    // sigmoid via exp2 (v_exp_f32); robust at extremes (inf -> 0/1, never NaN)
    return 1.0f / (1.0f + exp2f(x * -1.4426950408889634f));
}
__device__ __forceinline__ float ftanh(float x) {
    // tanh(x) = 2*sigmoid(2x) - 1 ; robust at extremes
    return 2.0f * fsig(2.0f * x) - 1.0f;
}

// ---------------- prep: bf16 conversions + zero init ----------------
__global__ void prep_kernel(const float* __restrict__ X, const float* __restrict__ Whq,
                            u16* __restrict__ Xb, u16* __restrict__ WqT,
                            u16* __restrict__ Hb, int* __restrict__ flags) {
    long gid = (long)blockIdx.x * blockDim.x + threadIdx.x;
    long stride = (long)gridDim.x * blockDim.x;
    // X -> bf16, vectorized x4 : 512*64*256 = 8388608 elems = 2097152 float4
    const float4* X4 = (const float4*)X;
    for (long i = gid; i < 2097152; i += stride) {
        float4 v = X4[i];
        u16x4 o;
        o.x = f2bf(v.x); o.y = f2bf(v.y); o.z = f2bf(v.z); o.w = f2bf(v.w);
        ((u16x4*)Xb)[i] = o;
    }
    // WqT[o][k] = bf16(Whq[k][o]) : 256*512 = 131072
    for (long i = gid; i < 131072; i += stride) {
        int o = (int)(i >> 9), k = (int)(i & 511);
        WqT[i] = f2bf(Whq[(long)k * 256 + o]);
    }
    // zero both parities of Hbuf: 2*64*512 u16 = 32768 ints
    for (long i = gid; i < 32768; i += stride) ((int*)Hb)[i] = 0;
    if (gid < 256) flags[gid] = 0;
}

// ---------------- recurrence: cooperative, 128 WGs x 256 thr ----------------
__global__ void lstm_rec(const u16* __restrict__ Xb, u16* __restrict__ Hb, int* __restrict__ flags,
                         const float* __restrict__ Wxi, const float* __restrict__ Wxf,
                         const float* __restrict__ Wxo, const float* __restrict__ Wxg,
                         const float* __restrict__ Whi, const float* __restrict__ Whf,
                         const float* __restrict__ Who, const float* __restrict__ Whg,
                         const float* __restrict__ bi, const float* __restrict__ bf_,
                         const float* __restrict__ bo, const float* __restrict__ bg,
                         float* __restrict__ Hs, float* __restrict__ Cs) {
    const int wg   = blockIdx.x;          // 0..127, owns h in [wg*4, wg*4+4)
    const int tid  = threadIdx.x;
    const int lane = tid & 63;
    const int wave = tid >> 6;            // 4 waves, 16 batch rows each
    const int c    = lane & 15;           // MFMA col / A-row-within-tile index
    const int hi4  = lane >> 4;           // 0..3
    const int gate = c >> 2;              // 0=i 1=f 2=o 3=g
    const int hloc = c & 3;
    const int h    = wg * 4 + hloc;       // global hidden column

    const float* Wx = (gate == 0) ? Wxi : (gate == 1) ? Wxf : (gate == 2) ? Wxo : Wxg;
    const float* Wh = (gate == 0) ? Whi : (gate == 1) ? Whf : (gate == 2) ? Who : Whg;
    const float* bp = (gate == 0) ? bi  : (gate == 1) ? bf_ : (gate == 2) ? bo  : bg;
    const float biasv = bp[h];

    // ---- preload this lane's B fragments (whole K=768) into registers ----
    bf16x8 Bf[24];
#pragma unroll
    for (int kt = 0; kt < 24; ++kt) {
        bf16x8 tmp;
#pragma unroll
        for (int j = 0; j < 8; ++j) {
            int k = kt * 32 + hi4 * 8 + j;
            float w = (k < II) ? Wx[(long)k * HH + h] : Wh[(long)(k - II) * HH + h];
            tmp[j] = (short)f2bf(w);
        }
        Bf[kt] = tmp;
    }

    const int arow = wave * 16 + c;                 // batch row this lane loads for A
    const u16* HbP0 = Hb + (long)arow * HH + hi4 * 8;
    const u16* HbP1 = Hb + (long)BB * HH + (long)arow * HH + hi4 * 8;
    const int browbase = wave * 16 + hi4 * 4;       // D-rows base for this lane
    const int srcbase = (lane & 48) | hloc;         // bpermute source base

    float cst[4] = {0.f, 0.f, 0.f, 0.f};

    for (int t = 0; t < TT; ++t) {
        const u16* xp = Xb + ((long)(t * BB + arow)) * II + hi4 * 8;
        const u16* hp = (t & 1) ? HbP1 : HbP0;

        fx4 acc0 = {biasv, biasv, biasv, biasv};
        fx4 acc1 = {0.f, 0.f, 0.f, 0.f};
#pragma unroll
        for (int kt = 0; kt < 8; ++kt) {
            bf16x8 a = *(const bf16x8*)(xp + kt * 32);
            if (kt & 1) acc1 = __builtin_amdgcn_mfma_f32_16x16x32_bf16(a, Bf[kt], acc1, 0, 0, 0);
            else        acc0 = __builtin_amdgcn_mfma_f32_16x16x32_bf16(a, Bf[kt], acc0, 0, 0, 0);
        }
#pragma unroll
        for (int kt = 0; kt < 16; ++kt) {
            bf16x8 a = *(const bf16x8*)(hp + kt * 32);
            if (kt & 1) acc1 = __builtin_amdgcn_mfma_f32_16x16x32_bf16(a, Bf[8 + kt], acc1, 0, 0, 0);
            else        acc0 = __builtin_amdgcn_mfma_f32_16x16x32_bf16(a, Bf[8 + kt], acc0, 0, 0, 0);
        }
        fx4 acc = acc0 + acc1;

        // gather all 4 gate preacts for h = wg*4 + hloc (every lane, 4x redundant)
        float pi[4], pf[4], po[4], pg[4];
#pragma unroll
        for (int r = 0; r < 4; ++r) {
            pi[r] = __shfl(acc[r], srcbase + 0);
            pf[r] = __shfl(acc[r], srcbase + 4);
            po[r] = __shfl(acc[r], srcbase + 8);
            pg[r] = __shfl(acc[r], srcbase + 12);
        }

        float* HsT = Hs + (long)t * BB * HH;
        float* CsT = Cs + (long)t * BB * HH;
        u16* HbW = Hb + (long)(((t + 1) & 1)) * BB * HH;
#pragma unroll
        for (int r = 0; r < 4; ++r) {
            float ig = fsig(pi[r]);
            float fg = fsig(pf[r]);
            float og = fsig(po[r]);
            float gg = ftanh(pg[r]);
            float cn = fg * cst[r] + ig * gg;
            cst[r] = cn;
            float hn = og * ftanh(cn);
            int brow = browbase + r;
            if (c < 4) {
                HsT[(long)brow * HH + h] = hn;
                CsT[(long)brow * HH + h] = cn;
            } else if (c < 8) {
                HbW[(long)brow * HH + h] = f2bf(hn);
            }
        }

        // ---- grid barrier: monotonic flags, release/acquire agent scope ----
        __syncthreads();
        if (tid == 0)
            __hip_atomic_store(&flags[wg], t + 1, __ATOMIC_RELEASE, __HIP_MEMORY_SCOPE_AGENT);
        if (tid < GRID_WG) {
            while (__hip_atomic_load(&flags[tid], __ATOMIC_ACQUIRE, __HIP_MEMORY_SCOPE_AGENT) < t + 1)
                __builtin_amdgcn_s_sleep(1);
        }
        __syncthreads();
        __builtin_amdgcn_fence(__ATOMIC_ACQUIRE, "agent");
    }
}

// ---------------- output GEMM: out = Hs @ WqT^T + bq ----------------
// M=32768 (T*B), N=256, K=512. WG = [64 rows, 64 cols], 4 waves of [16,64].
__global__ __launch_bounds__(256) void outgemm(const float* __restrict__ Hs,
                                               const u16* __restrict__ WqT,
                                               const float* __restrict__ bq,
                                               float* __restrict__ outp) {
    const int lane = threadIdx.x & 63, wave = threadIdx.x >> 6;
    const int cl = lane & 15, hi4 = lane >> 4;
    const int rowbase = blockIdx.x * 64 + wave * 16;
    const int colbase = blockIdx.y * 64;

    const float* Ap = Hs + (long)(rowbase + cl) * HH + hi4 * 8;
    fx4 acc[4];
#pragma unroll
    for (int n = 0; n < 4; ++n) acc[n] = (fx4){0.f, 0.f, 0.f, 0.f};

#pragma unroll
    for (int kt = 0; kt < 16; ++kt) {
        const float4* a4 = (const float4*)(Ap + kt * 32);
        float4 a0 = a4[0], a1 = a4[1];
        bf16x8 af;
        af[0] = (short)f2bf(a0.x); af[1] = (short)f2bf(a0.y);
        af[2] = (short)f2bf(a0.z); af[3] = (short)f2bf(a0.w);
        af[4] = (short)f2bf(a1.x); af[5] = (short)f2bf(a1.y);
        af[6] = (short)f2bf(a1.z); af[7] = (short)f2bf(a1.w);
#pragma unroll
        for (int n = 0; n < 4; ++n) {
            bf16x8 bfg = *(const bf16x8*)(WqT + (long)(colbase + n * 16 + cl) * HH + kt * 32 + hi4 * 8);
            acc[n] = __builtin_amdgcn_mfma_f32_16x16x32_bf16(af, bfg, acc[n], 0, 0, 0);
        }
    }
#pragma unroll
    for (int n = 0; n < 4; ++n) {
        int col = colbase + n * 16 + cl;
        float bv = bq[col];
#pragma unroll
        for (int r = 0; r < 4; ++r) {
            int row = rowbase + hi4 * 4 + r;
            outp[(long)row * OO + col] = acc[n][r] + bv;
        }
    }
}

extern "C" void kernel_launch(void* const* d_in, const int* in_sizes, int n_in,
                              void* d_out, int out_size, void* d_ws, size_t ws_size,
                              hipStream_t stream) {
    const float* X   = (const float*)d_in[0];
    const float* Wxi = (const float*)d_in[1];
    const float* Wxf = (const float*)d_in[2];
    const float* Wxo = (const float*)d_in[3];
    const float* Wxg = (const float*)d_in[4];
    const float* Whi = (const float*)d_in[5];
    const float* Whf = (const float*)d_in[6];
    const float* Who = (const float*)d_in[7];
    const float* Whg = (const float*)d_in[8];
    const float* bi  = (const float*)d_in[9];
    const float* bf_ = (const float*)d_in[10];
    const float* bo  = (const float*)d_in[11];
    const float* bg  = (const float*)d_in[12];
    const float* Whq = (const float*)d_in[13];
    const float* bq  = (const float*)d_in[14];

    float* outp = (float*)d_out;
    float* Hs = outp + (size_t)TT * BB * OO;          // 8388608
    float* Cs = Hs   + (size_t)TT * BB * HH;          // +16777216

    u16* Xb  = (u16*)d_ws;                            // 8388608 u16
    u16* WqT = Xb + (size_t)TT * BB * II;             // 131072 u16
    u16* Hb  = WqT + (size_t)OO * HH;                 // 65536 u16 (2 parities)
    int* flags = (int*)(Hb + (size_t)2 * BB * HH);    // 256 ints

    prep_kernel<<<2048, 256, 0, stream>>>(X, Whq, Xb, WqT, Hb, flags);

    void* args[17] = {
        (void*)&Xb, (void*)&Hb, (void*)&flags,
        (void*)&Wxi, (void*)&Wxf, (void*)&Wxo, (void*)&Wxg,
        (void*)&Whi, (void*)&Whf, (void*)&Who, (void*)&Whg,
        (void*)&bi, (void*)&bf_, (void*)&bo, (void*)&bg,
        (void*)&Hs, (void*)&Cs
    };
    hipLaunchCooperativeKernel((void*)lstm_rec, dim3(GRID_WG), dim3(256), args, 0, stream);

    outgemm<<<dim3(512, 4), 256, 0, stream>>>(Hs, WqT, bq, outp);
}

// Round 3
// 9686.476 us; speedup vs baseline: 1.0026x; 1.0026x over previous
//
#include <hip/hip_runtime.h>
#include <hip/hip_bf16.h>

typedef short bf16x8 __attribute__((ext_vector_type(8)));
typedef float fx4 __attribute__((ext_vector_type(4)));
typedef unsigned short u16;
typedef u16 u16x4 __attribute__((ext_vector_type(4)));

#define TT 512
#define BB 64
#define II 256
#define HH 512
#define OO 256
#define GRID_WG 128

__device__ __forceinline__ u16 f2bf(float f) {
    union { float f; unsigned u; } v; v.f = f;
    unsigned r = v.u + 0x7fffu + ((v.u >> 16) & 1u);
    return (u16)(r >> 16);
}

__device__ __forceinline__ float fsig(float x) {
    // sigmoid via exp2 (v_exp_f32); robust at extremes (inf -> 0/1, never NaN)
    return 1.0f / (1.0f + exp2f(x * -1.4426950408889634f));
}
__device__ __forceinline__ float ftanh(float x) {
    // tanh(x) = 2*sigmoid(2x) - 1 ; robust at extremes
    return 2.0f * fsig(2.0f * x) - 1.0f;
}

// ---------------- prep: bf16 conversions + zero init ----------------
__global__ void prep_kernel(const float* __restrict__ X, const float* __restrict__ Whq,
                            u16* __restrict__ Xb, u16* __restrict__ WqT,
                            u16* __restrict__ Hb, int* __restrict__ flags) {
    long gid = (long)blockIdx.x * blockDim.x + threadIdx.x;
    long stride = (long)gridDim.x * blockDim.x;
    // X -> bf16, vectorized x4 : 512*64*256 = 8388608 elems = 2097152 float4
    const float4* X4 = (const float4*)X;
    for (long i = gid; i < 2097152; i += stride) {
        float4 v = X4[i];
        u16x4 o;
        o.x = f2bf(v.x); o.y = f2bf(v.y); o.z = f2bf(v.z); o.w = f2bf(v.w);
        ((u16x4*)Xb)[i] = o;
    }
    // WqT[o][k] = bf16(Whq[k][o]) : 256*512 = 131072
    for (long i = gid; i < 131072; i += stride) {
        int o = (int)(i >> 9), k = (int)(i & 511);
        WqT[i] = f2bf(Whq[(long)k * 256 + o]);
    }
    // zero both parities of Hbuf: 2*64*512 u16 = 32768 ints
    for (long i = gid; i < 32768; i += stride) ((int*)Hb)[i] = 0;
    if (gid < 256) flags[gid] = 0;
}

// ---------------- recurrence: cooperative, 128 WGs x 256 thr ----------------
__global__ void lstm_rec(const u16* __restrict__ Xb, u16* __restrict__ Hb, int* __restrict__ flags,
                         const float* __restrict__ Wxi, const float* __restrict__ Wxf,
                         const float* __restrict__ Wxo, const float* __restrict__ Wxg,
                         const float* __restrict__ Whi, const float* __restrict__ Whf,
                         const float* __restrict__ Who, const float* __restrict__ Whg,
                         const float* __restrict__ bi, const float* __restrict__ bf_,
                         const float* __restrict__ bo, const float* __restrict__ bg,
                         float* __restrict__ Hs, float* __restrict__ Cs) {
    const int wg   = blockIdx.x;          // 0..127, owns h in [wg*4, wg*4+4)
    const int tid  = threadIdx.x;
    const int lane = tid & 63;
    const int wave = tid >> 6;            // 4 waves, 16 batch rows each
    const int c    = lane & 15;           // MFMA col / A-row-within-tile index
    const int hi4  = lane >> 4;           // 0..3
    const int gate = c >> 2;              // 0=i 1=f 2=o 3=g
    const int hloc = c & 3;
    const int h    = wg * 4 + hloc;       // global hidden column

    const float* Wx = (gate == 0) ? Wxi : (gate == 1) ? Wxf : (gate == 2) ? Wxo : Wxg;
    const float* Wh = (gate == 0) ? Whi : (gate == 1) ? Whf : (gate == 2) ? Who : Whg;
    const float* bp = (gate == 0) ? bi  : (gate == 1) ? bf_ : (gate == 2) ? bo  : bg;
    const float biasv = bp[h];

    // ---- preload this lane's B fragments (whole K=768) into registers ----
    bf16x8 Bf[24];
#pragma unroll
    for (int kt = 0; kt < 24; ++kt) {
        bf16x8 tmp;
#pragma unroll
        for (int j = 0; j < 8; ++j) {
            int k = kt * 32 + hi4 * 8 + j;
            float w = (k < II) ? Wx[(long)k * HH + h] : Wh[(long)(k - II) * HH + h];
            tmp[j] = (short)f2bf(w);
        }
        Bf[kt] = tmp;
    }

    const int arow = wave * 16 + c;                 // batch row this lane loads for A
    const u16* HbP0 = Hb + (long)arow * HH + hi4 * 8;
    const u16* HbP1 = Hb + (long)BB * HH + (long)arow * HH + hi4 * 8;
    const int browbase = wave * 16 + hi4 * 4;       // D-rows base for this lane
    const int srcbase = (lane & 48) | hloc;         // bpermute source base

    float cst[4] = {0.f, 0.f, 0.f, 0.f};

    for (int t = 0; t < TT; ++t) {
        const u16* xp = Xb + ((long)(t * BB + arow)) * II + hi4 * 8;
        const u16* hp = (t & 1) ? HbP1 : HbP0;

        fx4 acc0 = {biasv, biasv, biasv, biasv};
        fx4 acc1 = {0.f, 0.f, 0.f, 0.f};
#pragma unroll
        for (int kt = 0; kt < 8; ++kt) {
            bf16x8 a = *(const bf16x8*)(xp + kt * 32);
            if (kt & 1) acc1 = __builtin_amdgcn_mfma_f32_16x16x32_bf16(a, Bf[kt], acc1, 0, 0, 0);
            else        acc0 = __builtin_amdgcn_mfma_f32_16x16x32_bf16(a, Bf[kt], acc0, 0, 0, 0);
        }
#pragma unroll
        for (int kt = 0; kt < 16; ++kt) {
            bf16x8 a = *(const bf16x8*)(hp + kt * 32);
            if (kt & 1) acc1 = __builtin_amdgcn_mfma_f32_16x16x32_bf16(a, Bf[8 + kt], acc1, 0, 0, 0);
            else        acc0 = __builtin_amdgcn_mfma_f32_16x16x32_bf16(a, Bf[8 + kt], acc0, 0, 0, 0);
        }
        fx4 acc = acc0 + acc1;

        // gather all 4 gate preacts for h = wg*4 + hloc (every lane, 4x redundant)
        float pi[4], pf[4], po[4], pg[4];
#pragma unroll
        for (int r = 0; r < 4; ++r) {
            pi[r] = __shfl(acc[r], srcbase + 0);
            pf[r] = __shfl(acc[r], srcbase + 4);
            po[r] = __shfl(acc[r], srcbase + 8);
            pg[r] = __shfl(acc[r], srcbase + 12);
        }

        float* HsT = Hs + (long)t * BB * HH;
        float* CsT = Cs + (long)t * BB * HH;
        u16* HbW = Hb + (long)(((t + 1) & 1)) * BB * HH;
#pragma unroll
        for (int r = 0; r < 4; ++r) {
            float ig = fsig(pi[r]);
            float fg = fsig(pf[r]);
            float og = fsig(po[r]);
            float gg = ftanh(pg[r]);
            float cn = fg * cst[r] + ig * gg;
            cst[r] = cn;
            float hn = og * ftanh(cn);
            int brow = browbase + r;
            if (c < 4) {
                HsT[(long)brow * HH + h] = hn;
                CsT[(long)brow * HH + h] = cn;
            } else if (c < 8) {
                HbW[(long)brow * HH + h] = f2bf(hn);
            }
        }

        // ---- grid barrier: monotonic flags, release/acquire agent scope ----
        __syncthreads();
        if (tid == 0)
            __hip_atomic_store(&flags[wg], t + 1, __ATOMIC_RELEASE, __HIP_MEMORY_SCOPE_AGENT);
        if (tid < GRID_WG) {
            while (__hip_atomic_load(&flags[tid], __ATOMIC_ACQUIRE, __HIP_MEMORY_SCOPE_AGENT) < t + 1)
                __builtin_amdgcn_s_sleep(1);
        }
        __syncthreads();
        __builtin_amdgcn_fence(__ATOMIC_ACQUIRE, "agent");
    }
}

// ---------------- output GEMM: out = Hs @ WqT^T + bq ----------------
// M=32768 (T*B), N=256, K=512. WG = [64 rows, 64 cols], 4 waves of [16,64].
__global__ __launch_bounds__(256) void outgemm(const float* __restrict__ Hs,
                                               const u16* __restrict__ WqT,
                                               const float* __restrict__ bq,
                                               float* __restrict__ outp) {
    const int lane = threadIdx.x & 63, wave = threadIdx.x >> 6;
    const int cl = lane & 15, hi4 = lane >> 4;
    const int rowbase = blockIdx.x * 64 + wave * 16;
    const int colbase = blockIdx.y * 64;

    const float* Ap = Hs + (long)(rowbase + cl) * HH + hi4 * 8;
    fx4 acc[4];
#pragma unroll
    for (int n = 0; n < 4; ++n) acc[n] = (fx4){0.f, 0.f, 0.f, 0.f};

#pragma unroll
    for (int kt = 0; kt < 16; ++kt) {
        const float4* a4 = (const float4*)(Ap + kt * 32);
        float4 a0 = a4[0], a1 = a4[1];
        bf16x8 af;
        af[0] = (short)f2bf(a0.x); af[1] = (short)f2bf(a0.y);
        af[2] = (short)f2bf(a0.z); af[3] = (short)f2bf(a0.w);
        af[4] = (short)f2bf(a1.x); af[5] = (short)f2bf(a1.y);
        af[6] = (short)f2bf(a1.z); af[7] = (short)f2bf(a1.w);
#pragma unroll
        for (int n = 0; n < 4; ++n) {
            bf16x8 bfg = *(const bf16x8*)(WqT + (long)(colbase + n * 16 + cl) * HH + kt * 32 + hi4 * 8);
            acc[n] = __builtin_amdgcn_mfma_f32_16x16x32_bf16(af, bfg, acc[n], 0, 0, 0);
        }
    }
#pragma unroll
    for (int n = 0; n < 4; ++n) {
        int col = colbase + n * 16 + cl;
        float bv = bq[col];
#pragma unroll
        for (int r = 0; r < 4; ++r) {
            int row = rowbase + hi4 * 4 + r;
            outp[(long)row * OO + col] = acc[n][r] + bv;
        }
    }
}

extern "C" void kernel_launch(void* const* d_in, const int* in_sizes, int n_in,
                              void* d_out, int out_size, void* d_ws, size_t ws_size,
                              hipStream_t stream) {
    const float* X   = (const float*)d_in[0];
    const float* Wxi = (const float*)d_in[1];
    const float* Wxf = (const float*)d_in[2];
    const float* Wxo = (const float*)d_in[3];
    const float* Wxg = (const float*)d_in[4];
    const float* Whi = (const float*)d_in[5];
    const float* Whf = (const float*)d_in[6];
    const float* Who = (const float*)d_in[7];
    const float* Whg = (const float*)d_in[8];
    const float* bi  = (const float*)d_in[9];
    const float* bf_ = (const float*)d_in[10];
    const float* bo  = (const float*)d_in[11];
    const float* bg  = (const float*)d_in[12];
    const float* Whq = (const float*)d_in[13];
    const float* bq  = (const float*)d_in[14];

    float* outp = (float*)d_out;
    float* Hs = outp + (size_t)TT * BB * OO;          // 8388608
    float* Cs = Hs   + (size_t)TT * BB * HH;          // +16777216

    u16* Xb  = (u16*)d_ws;                            // 8388608 u16
    u16* WqT = Xb + (size_t)TT * BB * II;             // 131072 u16
    u16* Hb  = WqT + (size_t)OO * HH;                 // 65536 u16 (2 parities)
    int* flags = (int*)(Hb + (size_t)2 * BB * HH);    // 256 ints

    prep_kernel<<<2048, 256, 0, stream>>>(X, Whq, Xb, WqT, Hb, flags);

    void* args[17] = {
        (void*)&Xb, (void*)&Hb, (void*)&flags,
        (void*)&Wxi, (void*)&Wxf, (void*)&Wxo, (void*)&Wxg,
        (void*)&Whi, (void*)&Whf, (void*)&Who, (void*)&Whg,
        (void*)&bi, (void*)&bf_, (void*)&bo, (void*)&bg,
        (void*)&Hs, (void*)&Cs
    };
    hipLaunchCooperativeKernel((void*)lstm_rec, dim3(GRID_WG), dim3(256), args, 0, stream);

    outgemm<<<dim3(512, 4), 256, 0, stream>>>(Hs, WqT, bq, outp);
}

// Round 5
// 7441.053 us; speedup vs baseline: 1.3052x; 1.3018x over previous
//
#include <hip/hip_runtime.h>
#include <hip/hip_bf16.h>

typedef short bf16x8 __attribute__((ext_vector_type(8)));
typedef float fx4 __attribute__((ext_vector_type(4)));
typedef unsigned short u16;
typedef u16 u16x4 __attribute__((ext_vector_type(4)));

#define TT 512
#define BB 64
#define II 256
#define HH 512
#define OO 256
#define GRID_WG 128

__device__ __forceinline__ u16 f2bf(float f) {
    union { float f; unsigned u; } v; v.f = f;
    unsigned r = v.u + 0x7fffu + ((v.u >> 16) & 1u);
    return (u16)(r >> 16);
}

__device__ __forceinline__ float fsig(float x) {
    return 1.0f / (1.0f + exp2f(x * -1.4426950408889634f));
}
__device__ __forceinline__ float ftanh(float x) {
    return 2.0f * fsig(2.0f * x) - 1.0f;
}

// ---------------- prep: bf16 conversions + zero init ----------------
__global__ void prep_kernel(const float* __restrict__ X, const float* __restrict__ Whq,
                            u16* __restrict__ Xb, u16* __restrict__ WqT,
                            u16* __restrict__ Hb, int* __restrict__ flags) {
    long gid = (long)blockIdx.x * blockDim.x + threadIdx.x;
    long stride = (long)gridDim.x * blockDim.x;
    const float4* X4 = (const float4*)X;
    for (long i = gid; i < 2097152; i += stride) {
        float4 v = X4[i];
        u16x4 o;
        o.x = f2bf(v.x); o.y = f2bf(v.y); o.z = f2bf(v.z); o.w = f2bf(v.w);
        ((u16x4*)Xb)[i] = o;
    }
    for (long i = gid; i < 131072; i += stride) {
        int o = (int)(i >> 9), k = (int)(i & 511);
        WqT[i] = f2bf(Whq[(long)k * 256 + o]);
    }
    // zero both parities of Hbuf: 2*64*512 u16 = 32768 ints
    for (long i = gid; i < 32768; i += stride) ((int*)Hb)[i] = 0;
    if (gid < 256) flags[gid] = 0;
}

// ---------------- recurrence: cooperative, 128 WGs x 256 thr ----------------
// Weights fully in registers (launch_bounds(256,1) -> no spill). H exchanged
// via proven release/acquire pattern: syncthreads -> release-store flag
// (compiler emits L2 writeback + waitcnt) -> relaxed poll -> syncthreads ->
// ONE agent acquire fence (L1/L2 inv). X prefetched into registers before
// the fence so the invalidate doesn't force re-reads on the critical path.
__global__ __launch_bounds__(256, 1)
void lstm_rec(const u16* __restrict__ Xb, u16* __restrict__ Hb, int* __restrict__ flags,
              const float* __restrict__ Wxi, const float* __restrict__ Wxf,
              const float* __restrict__ Wxo, const float* __restrict__ Wxg,
              const float* __restrict__ Whi, const float* __restrict__ Whf,
              const float* __restrict__ Who, const float* __restrict__ Whg,
              const float* __restrict__ bi, const float* __restrict__ bf_,
              const float* __restrict__ bo, const float* __restrict__ bg,
              float* __restrict__ Hs, float* __restrict__ Cs) {
    const int wg   = blockIdx.x;          // 0..127, owns h in [wg*4, wg*4+4)
    const int tid  = threadIdx.x;
    const int lane = tid & 63;
    const int wave = tid >> 6;            // 4 waves, 16 batch rows each
    const int c    = lane & 15;           // MFMA col / A-row-within-tile index
    const int hi4  = lane >> 4;           // 0..3
    const int gate = c >> 2;              // 0=i 1=f 2=o 3=g
    const int hloc = c & 3;
    const int h    = wg * 4 + hloc;       // global hidden column

    const float* Wx = (gate == 0) ? Wxi : (gate == 1) ? Wxf : (gate == 2) ? Wxo : Wxg;
    const float* Wh = (gate == 0) ? Whi : (gate == 1) ? Whf : (gate == 2) ? Who : Whg;
    const float* bp = (gate == 0) ? bi  : (gate == 1) ? bf_ : (gate == 2) ? bo  : bg;
    const float biasv = bp[h];

    // ---- preload this lane's B fragments (whole K=768) into registers ----
    bf16x8 Bf[24];
#pragma unroll
    for (int kt = 0; kt < 24; ++kt) {
        bf16x8 tmp;
#pragma unroll
        for (int j = 0; j < 8; ++j) {
            int k = kt * 32 + hi4 * 8 + j;
            float w = (k < II) ? Wx[(long)k * HH + h] : Wh[(long)(k - II) * HH + h];
            tmp[j] = (short)f2bf(w);
        }
        Bf[kt] = tmp;
    }

    const int arow = wave * 16 + c;                 // batch row this lane loads for A
    const int browbase = wave * 16 + hi4 * 4;       // D-rows base for this lane
    const int srcbase = (lane & 48) | hloc;         // shfl source base

    // ---- preload X fragments for t=0 ----
    bf16x8 xf[8];
    {
        const u16* xp = Xb + (long)arow * II + hi4 * 8;
#pragma unroll
        for (int kt = 0; kt < 8; ++kt) xf[kt] = *(const bf16x8*)(xp + kt * 32);
    }

    float cst[4] = {0.f, 0.f, 0.f, 0.f};

    for (int t = 0; t < TT; ++t) {
        // 1. issue ALL H loads first (L2 is cold post-fence; go to LLC)
        bf16x8 hf[16];
        const u16* hp = Hb + ((t & 1) ? (long)BB * HH : 0) + (long)arow * HH + hi4 * 8;
#pragma unroll
        for (int kt = 0; kt < 16; ++kt) hf[kt] = *(const bf16x8*)(hp + kt * 32);

        // 2. X-part MFMAs (registers only — overlaps H-load latency)
        fx4 acc0 = {biasv, biasv, biasv, biasv};
        fx4 acc1 = {0.f, 0.f, 0.f, 0.f};
#pragma unroll
        for (int kt = 0; kt < 8; ++kt) {
            if (kt & 1) acc1 = __builtin_amdgcn_mfma_f32_16x16x32_bf16(xf[kt], Bf[kt], acc1, 0, 0, 0);
            else        acc0 = __builtin_amdgcn_mfma_f32_16x16x32_bf16(xf[kt], Bf[kt], acc0, 0, 0, 0);
        }

        // 3. prefetch next step's X tile into REGISTERS (survives the fence)
        bf16x8 xf2[8];
        if (t < TT - 1) {
            const u16* xp = Xb + ((long)((t + 1) * BB + arow)) * II + hi4 * 8;
#pragma unroll
            for (int kt = 0; kt < 8; ++kt) xf2[kt] = *(const bf16x8*)(xp + kt * 32);
        }

        // 4. H-part MFMAs
#pragma unroll
        for (int kt = 0; kt < 16; ++kt) {
            if (kt & 1) acc1 = __builtin_amdgcn_mfma_f32_16x16x32_bf16(hf[kt], Bf[8 + kt], acc1, 0, 0, 0);
            else        acc0 = __builtin_amdgcn_mfma_f32_16x16x32_bf16(hf[kt], Bf[8 + kt], acc0, 0, 0, 0);
        }
        fx4 acc = acc0 + acc1;

        // 5. gather gate preacts + elementwise gate math
        float cn[4], hn[4];
#pragma unroll
        for (int r = 0; r < 4; ++r) {
            float pi = __shfl(acc[r], srcbase + 0);
            float pf = __shfl(acc[r], srcbase + 4);
            float po = __shfl(acc[r], srcbase + 8);
            float pg = __shfl(acc[r], srcbase + 12);
            float ig = fsig(pi);
            float fg = fsig(pf);
            float og = fsig(po);
            float gg = ftanh(pg);
            float cv = fg * cst[r] + ig * gg;
            cst[r] = cv;
            cn[r] = cv;
            hn[r] = og * ftanh(cv);
        }

        // 6. H stores for next step (plain stores; published by the release)
        if (c >= 4 && c < 8) {
            u16* HbW = Hb + (long)(((t + 1) & 1)) * BB * HH;
#pragma unroll
            for (int r = 0; r < 4; ++r)
                HbW[(long)(browbase + r) * HH + h] = f2bf(hn[r]);
        }

        // 7. join WG (drains each wave's stores to L2), then publish:
        //    release-store emits buffer_wbl2 + s_waitcnt before the flag.
        __syncthreads();
        if (tid == 0)
            __hip_atomic_store(&flags[wg], t + 1, __ATOMIC_RELEASE, __HIP_MEMORY_SCOPE_AGENT);

        // 8. Hs/Cs fp32 stores — off the critical path, nontemporal
        if (c < 4) {
            float* HsT = Hs + (long)t * BB * HH;
            float* CsT = Cs + (long)t * BB * HH;
#pragma unroll
            for (int r = 0; r < 4; ++r) {
                __builtin_nontemporal_store(hn[r], &HsT[(long)(browbase + r) * HH + h]);
                __builtin_nontemporal_store(cn[r], &CsT[(long)(browbase + r) * HH + h]);
            }
        }

        // 9. wait for all WGs (relaxed poll — no per-iteration cache inv)
        if (tid < GRID_WG) {
            while (__hip_atomic_load(&flags[tid], __ATOMIC_RELAXED, __HIP_MEMORY_SCOPE_AGENT) < t + 1)
                __builtin_amdgcn_s_sleep(2);
        }
        __syncthreads();
        // 10. ONE acquire fence per step: invalidates L1/L2 so next H loads
        //     observe all WGs' published stores.
        __builtin_amdgcn_fence(__ATOMIC_ACQUIRE, "agent");

        // rotate X prefetch
        if (t < TT - 1) {
#pragma unroll
            for (int kt = 0; kt < 8; ++kt) xf[kt] = xf2[kt];
        }
    }
}

// ---------------- output GEMM: out = Hs @ WqT^T + bq ----------------
__global__ __launch_bounds__(256) void outgemm(const float* __restrict__ Hs,
                                               const u16* __restrict__ WqT,
                                               const float* __restrict__ bq,
                                               float* __restrict__ outp) {
    const int lane = threadIdx.x & 63, wave = threadIdx.x >> 6;
    const int cl = lane & 15, hi4 = lane >> 4;
    const int rowbase = blockIdx.x * 64 + wave * 16;
    const int colbase = blockIdx.y * 64;

    const float* Ap = Hs + (long)(rowbase + cl) * HH + hi4 * 8;
    fx4 acc[4];
#pragma unroll
    for (int n = 0; n < 4; ++n) acc[n] = (fx4){0.f, 0.f, 0.f, 0.f};

#pragma unroll
    for (int kt = 0; kt < 16; ++kt) {
        const float4* a4 = (const float4*)(Ap + kt * 32);
        float4 a0 = a4[0], a1 = a4[1];
        bf16x8 af;
        af[0] = (short)f2bf(a0.x); af[1] = (short)f2bf(a0.y);
        af[2] = (short)f2bf(a0.z); af[3] = (short)f2bf(a0.w);
        af[4] = (short)f2bf(a1.x); af[5] = (short)f2bf(a1.y);
        af[6] = (short)f2bf(a1.z); af[7] = (short)f2bf(a1.w);
#pragma unroll
        for (int n = 0; n < 4; ++n) {
            bf16x8 bfg = *(const bf16x8*)(WqT + (long)(colbase + n * 16 + cl) * HH + kt * 32 + hi4 * 8);
            acc[n] = __builtin_amdgcn_mfma_f32_16x16x32_bf16(af, bfg, acc[n], 0, 0, 0);
        }
    }
#pragma unroll
    for (int n = 0; n < 4; ++n) {
        int col = colbase + n * 16 + cl;
        float bv = bq[col];
#pragma unroll
        for (int r = 0; r < 4; ++r) {
            int row = rowbase + hi4 * 4 + r;
            outp[(long)row * OO + col] = acc[n][r] + bv;
        }
    }
}

extern "C" void kernel_launch(void* const* d_in, const int* in_sizes, int n_in,
                              void* d_out, int out_size, void* d_ws, size_t ws_size,
                              hipStream_t stream) {
    const float* X   = (const float*)d_in[0];
    const float* Wxi = (const float*)d_in[1];
    const float* Wxf = (const float*)d_in[2];
    const float* Wxo = (const float*)d_in[3];
    const float* Wxg = (const float*)d_in[4];
    const float* Whi = (const float*)d_in[5];
    const float* Whf = (const float*)d_in[6];
    const float* Who = (const float*)d_in[7];
    const float* Whg = (const float*)d_in[8];
    const float* bi  = (const float*)d_in[9];
    const float* bf_ = (const float*)d_in[10];
    const float* bo  = (const float*)d_in[11];
    const float* bg  = (const float*)d_in[12];
    const float* Whq = (const float*)d_in[13];
    const float* bq  = (const float*)d_in[14];

    float* outp = (float*)d_out;
    float* Hs = outp + (size_t)TT * BB * OO;          // 8388608
    float* Cs = Hs   + (size_t)TT * BB * HH;          // +16777216

    u16* Xb  = (u16*)d_ws;                            // 8388608 u16
    u16* WqT = Xb + (size_t)TT * BB * II;             // 131072 u16
    u16* Hb  = WqT + (size_t)OO * HH;                 // 65536 u16 (2 parities)
    int* flags = (int*)(Hb + (size_t)2 * BB * HH);    // 256 ints

    prep_kernel<<<2048, 256, 0, stream>>>(X, Whq, Xb, WqT, Hb, flags);

    void* args[17] = {
        (void*)&Xb, (void*)&Hb, (void*)&flags,
        (void*)&Wxi, (void*)&Wxf, (void*)&Wxo, (void*)&Wxg,
        (void*)&Whi, (void*)&Whf, (void*)&Who, (void*)&Whg,
        (void*)&bi, (void*)&bf_, (void*)&bo, (void*)&bg,
        (void*)&Hs, (void*)&Cs
    };
    hipLaunchCooperativeKernel((void*)lstm_rec, dim3(GRID_WG), dim3(256), args, 0, stream);

    outgemm<<<dim3(512, 4), 256, 0, stream>>>(Hs, WqT, bq, outp);
}